// Round 10
// baseline (1673.077 us; speedup 1.0000x reference)
//
#include <hip/hip_runtime.h>
#include <hip/hip_bf16.h>

// Problem constants (fixed by reference setup_inputs)
#define S_ROWS 4096
#define Q_ROWS 8192
#define DIM 256
#define N_SEL 19       // selection events (20 scan steps)
#define COLSPLIT 16    // phase-B column splits
#define BM 128         // phase-B rows per block
#define LDST 36        // phase-B LDS row stride (floats)
#define CB 32          // phase-C blocks
#define CT 1024        // phase-C threads per block
#define CR 256         // phase-C rows per block (4 threads per row)
#define SLOTS 4        // candidate slots per block per iteration

// Workspace layout (floats)
#define WS_INV_Q 0
#define WS_QQ    (WS_INV_Q + Q_ROWS)
#define WS_INV_S (WS_QQ + Q_ROWS)
#define WS_PP    (WS_INV_S + S_ROWS)
#define WS_TOP3P (WS_PP + S_ROWS)                    // [COLSPLIT][Q_ROWS][4]
#define WS_BMIN  (WS_TOP3P + COLSPLIT * Q_ROWS * 4)  // [32][CB]
#define WS_CANDU (WS_BMIN + 32 * CB)                 // [32][CB*SLOTS]
#define WS_CANDI (WS_CANDU + 32 * CB * SLOTS)        // [32][CB*SLOTS] (int)
#define WS_BAR   (WS_CANDI + 32 * CB * SLOTS)        // unsigned [32]

// ---------------------------------------------------------------------------
__global__ void norm_rows(const float* __restrict__ x, float* __restrict__ inv,
                          float* __restrict__ ssq, int nrows) {
    int w = (blockIdx.x * blockDim.x + threadIdx.x) >> 6;
    int lane = threadIdx.x & 63;
    if (w >= nrows) return;
    float4 v = reinterpret_cast<const float4*>(x + (size_t)w * DIM)[lane];
    float s = v.x * v.x + v.y * v.y + v.z * v.z + v.w * v.w;
#pragma unroll
    for (int o = 1; o < 64; o <<= 1) s += __shfl_xor(s, o, 64);
    float invn = 1.0f / sqrtf(s);
    float t = v.x * invn; float u = t * t;
    t = v.y * invn; u += t * t;
    t = v.z * invn; u += t * t;
    t = v.w * invn; u += t * t;
#pragma unroll
    for (int o = 1; o < 64; o <<= 1) u += __shfl_xor(u, o, 64);
    if (lane == 0) { inv[w] = invn; ssq[w] = u; }
}

// ---------------------------------------------------------------------------
__global__ void init_ws(unsigned* __restrict__ bar, float* __restrict__ out, int n_extra) {
    int t = blockIdx.x * blockDim.x + threadIdx.x;
    if (t < 32) bar[t] = 0u;
    if (t < n_extra) out[Q_ROWS + t] = 1.0f;
}

// ---------------------------------------------------------------------------
__device__ __forceinline__ void t3ins(float (&t3)[3], float d) {
    float mx = fmaxf(fmaxf(t3[0], t3[1]), t3[2]);
    if (d < mx) {
        if (t3[0] == mx) t3[0] = d;
        else if (t3[1] == mx) t3[1] = d;
        else t3[2] = d;
    }
}

__device__ __forceinline__ float smean3(float a, float b, float c) {
    float lo = fminf(fminf(a, b), c);
    float hi = fmaxf(fmaxf(a, b), c);
    float md = fminf(fmaxf(a, b), fminf(fmaxf(b, c), fmaxf(a, c)));
    return ((lo + md) + hi) * (1.0f / 3.0f);
}

// ---------------------------------------------------------------------------
// Phase B: fp32 GEMM + per-row top-3, async-STAGE split (T14):
//   s: { barrier; DSWRITE(regs->LDS, vmcnt drains here); barrier;
//        GLOAD(s+1)->regs (issued, NOT waited); compute(s); }
// Global latency hides under the ~4096-cycle FMA phase. Same full-line
// addresses (R5 lesson: half-line staging thrashes L2), same XOR swizzle,
// same __launch_bounds__(256,3) sweet spot (R6 tighter=spill, R8 looser=
// VGPR64 thrash). Extra cost: 32 VGPR for the in-flight tile.
__launch_bounds__(256, 3)
__global__ void knn_support_kernel(const float* __restrict__ qf, const float* __restrict__ sf,
                                   const float* __restrict__ inv_q, const float* __restrict__ inv_s,
                                   const float* __restrict__ qq, const float* __restrict__ pp,
                                   float* __restrict__ top3part) {
    __shared__ __align__(16) float As[BM * LDST];
    __shared__ __align__(16) float Bs[BM * LDST];

    int b0 = blockIdx.x;
    int rb = (b0 & 63) * BM;     // same-A blocks (all 16 cs) land on one XCD
    int cs = b0 >> 6;
    int tid = threadIdx.x;
    int tx = tid & 15, ty = tid >> 4;

    float t3[8][3];
#pragma unroll
    for (int i = 0; i < 8; ++i) t3[i][0] = t3[i][1] = t3[i][2] = INFINITY;
    float acc[8][8];
#pragma unroll
    for (int i = 0; i < 8; ++i)
#pragma unroll
        for (int j = 0; j < 8; ++j) acc[i][j] = 0.0f;

    float4 rgA[4], rgB[4];
    auto GLOAD = [&](int s) {            // s = 0..15: ch = s>>3, kt = s&7
        int ko = (s & 7) * 32;
        int cb = cs * 256 + (s >> 3) * 128;
#pragma unroll
        for (int q = 0; q < 4; ++q) {
            int idx = q * 256 + tid;
            int row = idx >> 3, f4 = idx & 7;
            rgA[q] = *reinterpret_cast<const float4*>(qf + (size_t)(rb + row) * DIM + ko + f4 * 4);
            rgB[q] = *reinterpret_cast<const float4*>(sf + (size_t)(cb + row) * DIM + ko + f4 * 4);
        }
    };
    auto DSWRITE = [&]() {
#pragma unroll
        for (int q = 0; q < 4; ++q) {
            int idx = q * 256 + tid;
            int row = idx >> 3, f4 = idx & 7;
            int slot = f4 ^ ((row >> 1) & 7);
            *reinterpret_cast<float4*>(As + row * LDST + (slot << 2)) = rgA[q];
            *reinterpret_cast<float4*>(Bs + row * LDST + (slot << 2)) = rgB[q];
        }
    };

    GLOAD(0);
    for (int s = 0; s < 16; ++s) {
        __syncthreads();   // previous tile's readers done before overwrite
        DSWRITE();         // vmcnt drains here (loads issued one step ago)
        __syncthreads();   // tile visible
        if (s + 1 < 16) GLOAD(s + 1);   // issue next tile; hide under compute
#pragma unroll
        for (int K = 0; K < 8; ++K) {
            int sA = ((K ^ (ty >> 1)) & 7) << 2;
            int sB = ((K ^ (tx >> 1)) & 7) << 2;
            float4 av[4], bva[4], bvb[4];
            // segment 1: i0-3 x j0-3
#pragma unroll
            for (int i = 0; i < 4; ++i)
                av[i] = *reinterpret_cast<const float4*>(As + (ty + 16 * i) * LDST + sA);
#pragma unroll
            for (int j = 0; j < 4; ++j)
                bva[j] = *reinterpret_cast<const float4*>(Bs + (tx + 16 * j) * LDST + sB);
#pragma unroll
            for (int i = 0; i < 4; ++i)
#pragma unroll
                for (int j = 0; j < 4; ++j) {
                    acc[i][j] += av[i].x * bva[j].x;
                    acc[i][j] += av[i].y * bva[j].y;
                    acc[i][j] += av[i].z * bva[j].z;
                    acc[i][j] += av[i].w * bva[j].w;
                }
            // segment 2: i0-3 x j4-7
#pragma unroll
            for (int j = 0; j < 4; ++j)
                bvb[j] = *reinterpret_cast<const float4*>(Bs + (tx + 16 * (4 + j)) * LDST + sB);
#pragma unroll
            for (int i = 0; i < 4; ++i)
#pragma unroll
                for (int j = 0; j < 4; ++j) {
                    acc[i][4 + j] += av[i].x * bvb[j].x;
                    acc[i][4 + j] += av[i].y * bvb[j].y;
                    acc[i][4 + j] += av[i].z * bvb[j].z;
                    acc[i][4 + j] += av[i].w * bvb[j].w;
                }
            // segment 3: i4-7 x j4-7 (av overwritten)
#pragma unroll
            for (int i = 0; i < 4; ++i)
                av[i] = *reinterpret_cast<const float4*>(As + (ty + 16 * (4 + i)) * LDST + sA);
#pragma unroll
            for (int i = 0; i < 4; ++i)
#pragma unroll
                for (int j = 0; j < 4; ++j) {
                    acc[4 + i][4 + j] += av[i].x * bvb[j].x;
                    acc[4 + i][4 + j] += av[i].y * bvb[j].y;
                    acc[4 + i][4 + j] += av[i].z * bvb[j].z;
                    acc[4 + i][4 + j] += av[i].w * bvb[j].w;
                }
            // segment 4: i4-7 x j0-3 (bva reloaded)
#pragma unroll
            for (int j = 0; j < 4; ++j)
                bva[j] = *reinterpret_cast<const float4*>(Bs + (tx + 16 * j) * LDST + sB);
#pragma unroll
            for (int i = 0; i < 4; ++i)
#pragma unroll
                for (int j = 0; j < 4; ++j) {
                    acc[4 + i][j] += av[i].x * bva[j].x;
                    acc[4 + i][j] += av[i].y * bva[j].y;
                    acc[4 + i][j] += av[i].z * bva[j].z;
                    acc[4 + i][j] += av[i].w * bva[j].w;
                }
        }
        if ((s & 7) == 7) {
            // epilogue for col-chunk: scale, distance, top-3; reset acc
            int cb = cs * 256 + (s >> 3) * 128;
            float ivb[8], ppc[8];
#pragma unroll
            for (int j = 0; j < 8; ++j) {
                ivb[j] = inv_s[cb + tx + 16 * j];
                ppc[j] = pp[cb + tx + 16 * j];
            }
#pragma unroll
            for (int i = 0; i < 8; ++i) {
                int r = rb + ty + 16 * i;
                float iva = inv_q[r];
                float qqr = qq[r];
#pragma unroll
                for (int j = 0; j < 8; ++j) {
                    float dot = acc[i][j] * iva * ivb[j];
                    float d2 = qqr + ppc[j] - 2.0f * dot;
                    float d = sqrtf(fmaxf(d2, 1e-12f));
                    t3ins(t3[i], d);
                    acc[i][j] = 0.0f;
                }
            }
        }
    }

    // merge per-row top3 across the 16 tx lanes (in-wave butterfly)
#pragma unroll
    for (int off = 1; off < 16; off <<= 1) {
#pragma unroll
        for (int i = 0; i < 8; ++i) {
            float o0 = __shfl_xor(t3[i][0], off, 64);
            float o1 = __shfl_xor(t3[i][1], off, 64);
            float o2 = __shfl_xor(t3[i][2], off, 64);
            t3ins(t3[i], o0);
            t3ins(t3[i], o1);
            t3ins(t3[i], o2);
        }
    }
    if (tx == 0) {
#pragma unroll
        for (int i = 0; i < 8; ++i) {
            float* dst = top3part + ((size_t)cs * Q_ROWS + rb + ty + 16 * i) * 4;
            dst[0] = t3[i][0]; dst[1] = t3[i][1]; dst[2] = t3[i][2]; dst[3] = 0.0f;
        }
    }
}

// ---------------------------------------------------------------------------
// Phase C (R9 proven, unchanged): 20 scan steps, one cooperative kernel.
// Only serialized global RMW is the barrier arrive; block-min and candidates
// go to per-block slots (plain stores, all written every iter -> replay-safe).
__global__ void iterate_select(const float* __restrict__ qf, const float* __restrict__ inv_q,
                               const float* __restrict__ qq, const float* __restrict__ top3part,
                               float* __restrict__ out, float* __restrict__ bmins,
                               float* __restrict__ candU, int* __restrict__ candI,
                               unsigned* __restrict__ bar) {
    __shared__ float t3s[CR][3];
    __shared__ float invs[CR], qqs[CR], scs[CR];
    __shared__ int kn[CR];
    __shared__ __align__(16) float qfc[DIM];
    __shared__ float red[CT / 64];
    __shared__ float bmin_sh, kth_sh;
    __shared__ int lidx[16];
    __shared__ int lcnt, ccnt;

    int tid = threadIdx.x;
    int bid = blockIdx.x;
    int rbase = bid * CR;
    int lane = tid & 63, wv = tid >> 6;

    if (tid < CR) {
        int r = rbase + tid;
        float b3[3] = {INFINITY, INFINITY, INFINITY};
        for (int csq = 0; csq < COLSPLIT; ++csq) {
            const float* p = top3part + ((size_t)csq * Q_ROWS + r) * 4;
            t3ins(b3, p[0]); t3ins(b3, p[1]); t3ins(b3, p[2]);
        }
        t3s[tid][0] = b3[0]; t3s[tid][1] = b3[1]; t3s[tid][2] = b3[2];
        invs[tid] = inv_q[r];
        qqs[tid] = qq[r];
        kn[tid] = 0;
    }
    __syncthreads();

    for (int t = 0; t <= N_SEL; ++t) {
        if (t > 0) {
            // kth = min over CB block-mins published at t-1 (local recompute)
            if (tid == 0) lcnt = 0;
            if (wv == 0 && lane < CB) {
                float v = bmins[(t - 1) * CB + lane];
#pragma unroll
                for (int o = 1; o < CB; o <<= 1) v = fminf(v, __shfl_xor(v, o, 64));
                if (lane == 0) kth_sh = v;
            }
            __syncthreads();
            float kth = kth_sh;
            // gather globally-selected candidates from per-block slots
            if (tid < CB * SLOTS) {
                float u = candU[(t - 1) * CB * SLOTS + tid];
                if (u <= kth) {
                    int p = atomicAdd(&lcnt, 1);
                    if (p < 16) lidx[p] = candI[(t - 1) * CB * SLOTS + tid];
                }
            }
            __syncthreads();
            int m = lcnt < 16 ? lcnt : 16;
            for (int j = 0; j < m; ++j) {
                int c = lidx[j];
                if (tid == 0 && c >= rbase && c < rbase + CR) kn[c - rbase] = 1;
                if (tid < DIM) qfc[tid] = qf[(size_t)c * DIM + tid] * inv_q[c];
                __syncthreads();
                float qqc = qq[c];
                // 4 threads per row (R7 exact order -> absmax 0.0)
                int row = tid >> 2, sub = tid & 3;
                const float4* rp = reinterpret_cast<const float4*>(qf + (size_t)(rbase + row) * DIM);
                const float4* cp = reinterpret_cast<const float4*>(qfc);
                float si = invs[row];
                float d = 0.0f;
#pragma unroll
                for (int i2 = 0; i2 < 16; ++i2) {
                    float4 v = rp[sub + 4 * i2];
                    float4 w = cp[sub + 4 * i2];
                    d += (v.x * si) * w.x;
                    d += (v.y * si) * w.y;
                    d += (v.z * si) * w.z;
                    d += (v.w * si) * w.w;
                }
                d += __shfl_xor(d, 1, 64);
                d += __shfl_xor(d, 2, 64);
                if (sub == 0) {
                    float d2 = qqs[row] + qqc - 2.0f * d;
                    float dist = sqrtf(fmaxf(d2, 1e-12f));
                    float b3[3] = {t3s[row][0], t3s[row][1], t3s[row][2]};
                    t3ins(b3, dist);
                    t3s[row][0] = b3[0]; t3s[row][1] = b3[1]; t3s[row][2] = b3[2];
                }
                __syncthreads();
            }
            __syncthreads();
        }

        if (t == N_SEL) {
            if (tid < CR)
                out[rbase + tid] = 1.0f - smean3(t3s[tid][0], t3s[tid][1], t3s[tid][2]);
            return;
        }

        // scores (inf = known)
        if (tid == 0) ccnt = 0;
        if (tid < CR)
            scs[tid] = kn[tid] ? INFINITY : smean3(t3s[tid][0], t3s[tid][1], t3s[tid][2]);
        __syncthreads();

        // block min over CR rows
        float mn = (tid < CR) ? scs[tid] : INFINITY;
#pragma unroll
        for (int o = 1; o < 64; o <<= 1) mn = fminf(mn, __shfl_xor(mn, o, 64));
        if (lane == 0) red[wv] = mn;
        __syncthreads();
        if (tid == 0) {
            float v = red[0];
#pragma unroll
            for (int i = 1; i < CT / 64; ++i) v = fminf(v, red[i]);
            bmin_sh = v;
            bmins[t * CB + bid] = v;                 // per-block slot, no atomic
        }
        __syncthreads();
        float bmin = bmin_sh;
        // publish block-min ties into my block's SLOTS (LDS-atomic ordering)
        if (tid < CR && scs[tid] == bmin) {
            int p = atomicAdd(&ccnt, 1);
            if (p < SLOTS) {
                candU[t * CB * SLOTS + bid * SLOTS + p] = scs[tid];
                candI[t * CB * SLOTS + bid * SLOTS + p] = rbase + tid;
            }
        }
        __syncthreads();
        if (tid == 0) {
            for (int p = ccnt; p < SLOTS; ++p) {     // fill unused slots (replay-safe)
                candU[t * CB * SLOTS + bid * SLOTS + p] = INFINITY;
                candI[t * CB * SLOTS + bid * SLOTS + p] = 0;
            }
            // barrier: release arrive + relaxed spin + acquire fence
            __hip_atomic_fetch_add(&bar[t], 1u, __ATOMIC_RELEASE, __HIP_MEMORY_SCOPE_AGENT);
            while (__hip_atomic_load(&bar[t], __ATOMIC_RELAXED, __HIP_MEMORY_SCOPE_AGENT) < CB)
                __builtin_amdgcn_s_sleep(2);
            __threadfence();
        }
        __syncthreads();
    }
}

// ---------------------------------------------------------------------------
extern "C" void kernel_launch(void* const* d_in, const int* in_sizes, int n_in,
                              void* d_out, int out_size, void* d_ws, size_t ws_size,
                              hipStream_t stream) {
    const float* sfeat = (const float*)d_in[0];
    const float* qfeat = (const float*)d_in[2];
    float* out = (float*)d_out;

    float* ws = (float*)d_ws;
    float* inv_q = ws + WS_INV_Q;
    float* qq    = ws + WS_QQ;
    float* inv_s = ws + WS_INV_S;
    float* pp    = ws + WS_PP;
    float* top3p = ws + WS_TOP3P;
    float* bmins = ws + WS_BMIN;
    float* candU = ws + WS_CANDU;
    int* candI   = (int*)(ws + WS_CANDI);
    unsigned* bar = (unsigned*)(ws + WS_BAR);

    int n_extra = out_size - Q_ROWS;
    if (n_extra < 0) n_extra = 0;

    norm_rows<<<Q_ROWS * 64 / 256, 256, 0, stream>>>(qfeat, inv_q, qq, Q_ROWS);
    norm_rows<<<S_ROWS * 64 / 256, 256, 0, stream>>>(sfeat, inv_s, pp, S_ROWS);
    init_ws<<<32, 256, 0, stream>>>(bar, out, n_extra);
    knn_support_kernel<<<64 * COLSPLIT, 256, 0, stream>>>(qfeat, sfeat, inv_q, inv_s, qq, pp, top3p);

    const float* a0 = qfeat; const float* a1 = inv_q; const float* a2 = qq;
    const float* a3 = top3p; float* a4 = out;
    float* a5 = bmins; float* a6 = candU; int* a7 = candI; unsigned* a8 = bar;
    void* cargs[] = {&a0, &a1, &a2, &a3, &a4, &a5, &a6, &a7, &a8};
    hipLaunchCooperativeKernel(iterate_select, dim3(CB), dim3(CT), cargs, 0, stream);
}

// Round 11
// 470.423 us; speedup vs baseline: 3.5565x; 3.5565x over previous
//
#include <hip/hip_runtime.h>
#include <hip/hip_bf16.h>

// Problem constants (fixed by reference setup_inputs)
#define S_ROWS 4096
#define Q_ROWS 8192
#define DIM 256
#define N_SEL 19       // selection events (20 scan steps)
#define COLSPLIT 32    // phase-B column splits (128 cols per block; 2048 blocks
                       // = 2.67x the 768 resident slots -> 89% tail utilization
                       // vs 67% at COLSPLIT=16 [R9: VALUBusy 62% == tail math])
#define BM 128         // phase-B rows per block
#define LDST 36        // phase-B LDS row stride (floats)
#define CB 32          // phase-C blocks
#define CT 1024        // phase-C threads per block
#define CR 256         // phase-C rows per block (4 threads per row)
#define SLOTS 4        // candidate slots per block per iteration

// Workspace layout (floats)
#define WS_INV_Q 0
#define WS_QQ    (WS_INV_Q + Q_ROWS)
#define WS_INV_S (WS_QQ + Q_ROWS)
#define WS_PP    (WS_INV_S + S_ROWS)
#define WS_TOP3P (WS_PP + S_ROWS)                    // [COLSPLIT][Q_ROWS][4]
#define WS_BMIN  (WS_TOP3P + COLSPLIT * Q_ROWS * 4)  // [32][CB]
#define WS_CANDU (WS_BMIN + 32 * CB)                 // [32][CB*SLOTS]
#define WS_CANDI (WS_CANDU + 32 * CB * SLOTS)        // [32][CB*SLOTS] (int)
#define WS_BAR   (WS_CANDI + 32 * CB * SLOTS)        // unsigned [32]

// ---------------------------------------------------------------------------
__global__ void norm_rows(const float* __restrict__ x, float* __restrict__ inv,
                          float* __restrict__ ssq, int nrows) {
    int w = (blockIdx.x * blockDim.x + threadIdx.x) >> 6;
    int lane = threadIdx.x & 63;
    if (w >= nrows) return;
    float4 v = reinterpret_cast<const float4*>(x + (size_t)w * DIM)[lane];
    float s = v.x * v.x + v.y * v.y + v.z * v.z + v.w * v.w;
#pragma unroll
    for (int o = 1; o < 64; o <<= 1) s += __shfl_xor(s, o, 64);
    float invn = 1.0f / sqrtf(s);
    float t = v.x * invn; float u = t * t;
    t = v.y * invn; u += t * t;
    t = v.z * invn; u += t * t;
    t = v.w * invn; u += t * t;
#pragma unroll
    for (int o = 1; o < 64; o <<= 1) u += __shfl_xor(u, o, 64);
    if (lane == 0) { inv[w] = invn; ssq[w] = u; }
}

// ---------------------------------------------------------------------------
__global__ void init_ws(unsigned* __restrict__ bar, float* __restrict__ out, int n_extra) {
    int t = blockIdx.x * blockDim.x + threadIdx.x;
    if (t < 32) bar[t] = 0u;
    if (t < n_extra) out[Q_ROWS + t] = 1.0f;
}

// ---------------------------------------------------------------------------
__device__ __forceinline__ void t3ins(float (&t3)[3], float d) {
    float mx = fmaxf(fmaxf(t3[0], t3[1]), t3[2]);
    if (d < mx) {
        if (t3[0] == mx) t3[0] = d;
        else if (t3[1] == mx) t3[1] = d;
        else t3[2] = d;
    }
}

__device__ __forceinline__ float smean3(float a, float b, float c) {
    float lo = fminf(fminf(a, b), c);
    float hi = fmaxf(fmaxf(a, b), c);
    float md = fminf(fmaxf(a, b), fminf(fmaxf(b, c), fmaxf(a, c)));
    return ((lo + md) + hi) * (1.0f / 3.0f);
}

// ---------------------------------------------------------------------------
// Phase B: fp32 GEMM + per-row top-3. R7/R9 proven body (R10's reg-prefetch
// spilled: WRITE_SIZE 4.25 GB -> reverted). One 128-col chunk per block.
// __launch_bounds__(256,3) is the measured regalloc sweet spot: R6 tighter =
// spill, R8 looser = VGPR64 + L2 thrash. Same k-accumulation order as R9
// (bitwise-identical distances -> absmax 0.0).
__launch_bounds__(256, 3)
__global__ void knn_support_kernel(const float* __restrict__ qf, const float* __restrict__ sf,
                                   const float* __restrict__ inv_q, const float* __restrict__ inv_s,
                                   const float* __restrict__ qq, const float* __restrict__ pp,
                                   float* __restrict__ top3part) {
    __shared__ __align__(16) float As[BM * LDST];
    __shared__ __align__(16) float Bs[BM * LDST];

    int b0 = blockIdx.x;
    int rb = (b0 & 63) * BM;     // same-A blocks (all 32 cs) spread across XCDs by rb
    int cs = b0 >> 6;            // 0..31
    int cb = cs * 128;
    int tid = threadIdx.x;
    int tx = tid & 15, ty = tid >> 4;

    float t3[8][3];
#pragma unroll
    for (int i = 0; i < 8; ++i) t3[i][0] = t3[i][1] = t3[i][2] = INFINITY;

    float acc[8][8];
#pragma unroll
    for (int i = 0; i < 8; ++i)
#pragma unroll
        for (int j = 0; j < 8; ++j) acc[i][j] = 0.0f;

    for (int kt = 0; kt < 8; ++kt) {
        int ko = kt * 32;
        __syncthreads();   // previous tile's readers done before overwrite
#pragma unroll
        for (int q = 0; q < 4; ++q) {
            int idx = q * 256 + tid;
            int row = idx >> 3, f4 = idx & 7;
            int slot = f4 ^ ((row >> 1) & 7);
            float4 a = *reinterpret_cast<const float4*>(qf + (size_t)(rb + row) * DIM + ko + f4 * 4);
            *reinterpret_cast<float4*>(As + row * LDST + (slot << 2)) = a;
            float4 b = *reinterpret_cast<const float4*>(sf + (size_t)(cb + row) * DIM + ko + f4 * 4);
            *reinterpret_cast<float4*>(Bs + row * LDST + (slot << 2)) = b;
        }
        __syncthreads();
#pragma unroll
        for (int K = 0; K < 8; ++K) {
            int sA = ((K ^ (ty >> 1)) & 7) << 2;
            int sB = ((K ^ (tx >> 1)) & 7) << 2;
            float4 av[4], bva[4], bvb[4];
            // segment 1: i0-3 x j0-3
#pragma unroll
            for (int i = 0; i < 4; ++i)
                av[i] = *reinterpret_cast<const float4*>(As + (ty + 16 * i) * LDST + sA);
#pragma unroll
            for (int j = 0; j < 4; ++j)
                bva[j] = *reinterpret_cast<const float4*>(Bs + (tx + 16 * j) * LDST + sB);
#pragma unroll
            for (int i = 0; i < 4; ++i)
#pragma unroll
                for (int j = 0; j < 4; ++j) {
                    acc[i][j] += av[i].x * bva[j].x;
                    acc[i][j] += av[i].y * bva[j].y;
                    acc[i][j] += av[i].z * bva[j].z;
                    acc[i][j] += av[i].w * bva[j].w;
                }
            // segment 2: i0-3 x j4-7
#pragma unroll
            for (int j = 0; j < 4; ++j)
                bvb[j] = *reinterpret_cast<const float4*>(Bs + (tx + 16 * (4 + j)) * LDST + sB);
#pragma unroll
            for (int i = 0; i < 4; ++i)
#pragma unroll
                for (int j = 0; j < 4; ++j) {
                    acc[i][4 + j] += av[i].x * bvb[j].x;
                    acc[i][4 + j] += av[i].y * bvb[j].y;
                    acc[i][4 + j] += av[i].z * bvb[j].z;
                    acc[i][4 + j] += av[i].w * bvb[j].w;
                }
            // segment 3: i4-7 x j4-7 (av overwritten)
#pragma unroll
            for (int i = 0; i < 4; ++i)
                av[i] = *reinterpret_cast<const float4*>(As + (ty + 16 * (4 + i)) * LDST + sA);
#pragma unroll
            for (int i = 0; i < 4; ++i)
#pragma unroll
                for (int j = 0; j < 4; ++j) {
                    acc[4 + i][4 + j] += av[i].x * bvb[j].x;
                    acc[4 + i][4 + j] += av[i].y * bvb[j].y;
                    acc[4 + i][4 + j] += av[i].z * bvb[j].z;
                    acc[4 + i][4 + j] += av[i].w * bvb[j].w;
                }
            // segment 4: i4-7 x j0-3 (bva reloaded)
#pragma unroll
            for (int j = 0; j < 4; ++j)
                bva[j] = *reinterpret_cast<const float4*>(Bs + (tx + 16 * j) * LDST + sB);
#pragma unroll
            for (int i = 0; i < 4; ++i)
#pragma unroll
                for (int j = 0; j < 4; ++j) {
                    acc[4 + i][j] += av[i].x * bva[j].x;
                    acc[4 + i][j] += av[i].y * bva[j].y;
                    acc[4 + i][j] += av[i].z * bva[j].z;
                    acc[4 + i][j] += av[i].w * bva[j].w;
                }
        }
    }
    // epilogue: scale, distance, top-3
    {
        float ivb[8], ppc[8];
#pragma unroll
        for (int j = 0; j < 8; ++j) {
            ivb[j] = inv_s[cb + tx + 16 * j];
            ppc[j] = pp[cb + tx + 16 * j];
        }
#pragma unroll
        for (int i = 0; i < 8; ++i) {
            int r = rb + ty + 16 * i;
            float iva = inv_q[r];
            float qqr = qq[r];
#pragma unroll
            for (int j = 0; j < 8; ++j) {
                float dot = acc[i][j] * iva * ivb[j];
                float d2 = qqr + ppc[j] - 2.0f * dot;
                float d = sqrtf(fmaxf(d2, 1e-12f));
                t3ins(t3[i], d);
            }
        }
    }

    // merge per-row top3 across the 16 tx lanes (in-wave butterfly)
#pragma unroll
    for (int off = 1; off < 16; off <<= 1) {
#pragma unroll
        for (int i = 0; i < 8; ++i) {
            float o0 = __shfl_xor(t3[i][0], off, 64);
            float o1 = __shfl_xor(t3[i][1], off, 64);
            float o2 = __shfl_xor(t3[i][2], off, 64);
            t3ins(t3[i], o0);
            t3ins(t3[i], o1);
            t3ins(t3[i], o2);
        }
    }
    if (tx == 0) {
#pragma unroll
        for (int i = 0; i < 8; ++i) {
            float* dst = top3part + ((size_t)cs * Q_ROWS + rb + ty + 16 * i) * 4;
            dst[0] = t3[i][0]; dst[1] = t3[i][1]; dst[2] = t3[i][2]; dst[3] = 0.0f;
        }
    }
}

// ---------------------------------------------------------------------------
// Phase C (R9 proven, unchanged except COLSPLIT=32 in stage-in): 20 scan
// steps, one cooperative kernel. Only serialized global RMW is the barrier
// arrive; block-min and candidates go to per-block slots (plain stores,
// all written every iter -> replay-safe).
__global__ void iterate_select(const float* __restrict__ qf, const float* __restrict__ inv_q,
                               const float* __restrict__ qq, const float* __restrict__ top3part,
                               float* __restrict__ out, float* __restrict__ bmins,
                               float* __restrict__ candU, int* __restrict__ candI,
                               unsigned* __restrict__ bar) {
    __shared__ float t3s[CR][3];
    __shared__ float invs[CR], qqs[CR], scs[CR];
    __shared__ int kn[CR];
    __shared__ __align__(16) float qfc[DIM];
    __shared__ float red[CT / 64];
    __shared__ float bmin_sh, kth_sh;
    __shared__ int lidx[16];
    __shared__ int lcnt, ccnt;

    int tid = threadIdx.x;
    int bid = blockIdx.x;
    int rbase = bid * CR;
    int lane = tid & 63, wv = tid >> 6;

    if (tid < CR) {
        int r = rbase + tid;
        float b3[3] = {INFINITY, INFINITY, INFINITY};
        for (int csq = 0; csq < COLSPLIT; ++csq) {
            const float* p = top3part + ((size_t)csq * Q_ROWS + r) * 4;
            t3ins(b3, p[0]); t3ins(b3, p[1]); t3ins(b3, p[2]);
        }
        t3s[tid][0] = b3[0]; t3s[tid][1] = b3[1]; t3s[tid][2] = b3[2];
        invs[tid] = inv_q[r];
        qqs[tid] = qq[r];
        kn[tid] = 0;
    }
    __syncthreads();

    for (int t = 0; t <= N_SEL; ++t) {
        if (t > 0) {
            // kth = min over CB block-mins published at t-1 (local recompute)
            if (tid == 0) lcnt = 0;
            if (wv == 0 && lane < CB) {
                float v = bmins[(t - 1) * CB + lane];
#pragma unroll
                for (int o = 1; o < CB; o <<= 1) v = fminf(v, __shfl_xor(v, o, 64));
                if (lane == 0) kth_sh = v;
            }
            __syncthreads();
            float kth = kth_sh;
            // gather globally-selected candidates from per-block slots
            if (tid < CB * SLOTS) {
                float u = candU[(t - 1) * CB * SLOTS + tid];
                if (u <= kth) {
                    int p = atomicAdd(&lcnt, 1);
                    if (p < 16) lidx[p] = candI[(t - 1) * CB * SLOTS + tid];
                }
            }
            __syncthreads();
            int m = lcnt < 16 ? lcnt : 16;
            for (int j = 0; j < m; ++j) {
                int c = lidx[j];
                if (tid == 0 && c >= rbase && c < rbase + CR) kn[c - rbase] = 1;
                if (tid < DIM) qfc[tid] = qf[(size_t)c * DIM + tid] * inv_q[c];
                __syncthreads();
                float qqc = qq[c];
                // 4 threads per row (R7 exact order -> absmax 0.0)
                int row = tid >> 2, sub = tid & 3;
                const float4* rp = reinterpret_cast<const float4*>(qf + (size_t)(rbase + row) * DIM);
                const float4* cp = reinterpret_cast<const float4*>(qfc);
                float si = invs[row];
                float d = 0.0f;
#pragma unroll
                for (int i2 = 0; i2 < 16; ++i2) {
                    float4 v = rp[sub + 4 * i2];
                    float4 w = cp[sub + 4 * i2];
                    d += (v.x * si) * w.x;
                    d += (v.y * si) * w.y;
                    d += (v.z * si) * w.z;
                    d += (v.w * si) * w.w;
                }
                d += __shfl_xor(d, 1, 64);
                d += __shfl_xor(d, 2, 64);
                if (sub == 0) {
                    float d2 = qqs[row] + qqc - 2.0f * d;
                    float dist = sqrtf(fmaxf(d2, 1e-12f));
                    float b3[3] = {t3s[row][0], t3s[row][1], t3s[row][2]};
                    t3ins(b3, dist);
                    t3s[row][0] = b3[0]; t3s[row][1] = b3[1]; t3s[row][2] = b3[2];
                }
                __syncthreads();
            }
            __syncthreads();
        }

        if (t == N_SEL) {
            if (tid < CR)
                out[rbase + tid] = 1.0f - smean3(t3s[tid][0], t3s[tid][1], t3s[tid][2]);
            return;
        }

        // scores (inf = known)
        if (tid == 0) ccnt = 0;
        if (tid < CR)
            scs[tid] = kn[tid] ? INFINITY : smean3(t3s[tid][0], t3s[tid][1], t3s[tid][2]);
        __syncthreads();

        // block min over CR rows
        float mn = (tid < CR) ? scs[tid] : INFINITY;
#pragma unroll
        for (int o = 1; o < 64; o <<= 1) mn = fminf(mn, __shfl_xor(mn, o, 64));
        if (lane == 0) red[wv] = mn;
        __syncthreads();
        if (tid == 0) {
            float v = red[0];
#pragma unroll
            for (int i = 1; i < CT / 64; ++i) v = fminf(v, red[i]);
            bmin_sh = v;
            bmins[t * CB + bid] = v;                 // per-block slot, no atomic
        }
        __syncthreads();
        float bmin = bmin_sh;
        // publish block-min ties into my block's SLOTS (LDS-atomic ordering)
        if (tid < CR && scs[tid] == bmin) {
            int p = atomicAdd(&ccnt, 1);
            if (p < SLOTS) {
                candU[t * CB * SLOTS + bid * SLOTS + p] = scs[tid];
                candI[t * CB * SLOTS + bid * SLOTS + p] = rbase + tid;
            }
        }
        __syncthreads();
        if (tid == 0) {
            for (int p = ccnt; p < SLOTS; ++p) {     // fill unused slots (replay-safe)
                candU[t * CB * SLOTS + bid * SLOTS + p] = INFINITY;
                candI[t * CB * SLOTS + bid * SLOTS + p] = 0;
            }
            // barrier: release arrive + relaxed spin + acquire fence
            __hip_atomic_fetch_add(&bar[t], 1u, __ATOMIC_RELEASE, __HIP_MEMORY_SCOPE_AGENT);
            while (__hip_atomic_load(&bar[t], __ATOMIC_RELAXED, __HIP_MEMORY_SCOPE_AGENT) < CB)
                __builtin_amdgcn_s_sleep(2);
            __threadfence();
        }
        __syncthreads();
    }
}

// ---------------------------------------------------------------------------
extern "C" void kernel_launch(void* const* d_in, const int* in_sizes, int n_in,
                              void* d_out, int out_size, void* d_ws, size_t ws_size,
                              hipStream_t stream) {
    const float* sfeat = (const float*)d_in[0];
    const float* qfeat = (const float*)d_in[2];
    float* out = (float*)d_out;

    float* ws = (float*)d_ws;
    float* inv_q = ws + WS_INV_Q;
    float* qq    = ws + WS_QQ;
    float* inv_s = ws + WS_INV_S;
    float* pp    = ws + WS_PP;
    float* top3p = ws + WS_TOP3P;
    float* bmins = ws + WS_BMIN;
    float* candU = ws + WS_CANDU;
    int* candI   = (int*)(ws + WS_CANDI);
    unsigned* bar = (unsigned*)(ws + WS_BAR);

    int n_extra = out_size - Q_ROWS;
    if (n_extra < 0) n_extra = 0;

    norm_rows<<<Q_ROWS * 64 / 256, 256, 0, stream>>>(qfeat, inv_q, qq, Q_ROWS);
    norm_rows<<<S_ROWS * 64 / 256, 256, 0, stream>>>(sfeat, inv_s, pp, S_ROWS);
    init_ws<<<32, 256, 0, stream>>>(bar, out, n_extra);
    knn_support_kernel<<<64 * COLSPLIT, 256, 0, stream>>>(qfeat, sfeat, inv_q, inv_s, qq, pp, top3p);

    const float* a0 = qfeat; const float* a1 = inv_q; const float* a2 = qq;
    const float* a3 = top3p; float* a4 = out;
    float* a5 = bmins; float* a6 = candU; int* a7 = candI; unsigned* a8 = bar;
    void* cargs[] = {&a0, &a1, &a2, &a3, &a4, &a5, &a6, &a7, &a8};
    hipLaunchCooperativeKernel(iterate_select, dim3(CB), dim3(CT), cargs, 0, stream);
}